// Round 16
// baseline (1122.876 us; speedup 1.0000x reference)
//
#include <hip/hip_runtime.h>
#include <hip/hip_bf16.h>

#define DIM 4096
#define HROWS 54
#define HSZ (54 * 4096)
#define SPLITK 16
#define KSLICE 256

typedef __attribute__((ext_vector_type(4))) float  f32x4;
typedef __attribute__((ext_vector_type(8))) short  s16x8;
typedef __attribute__((ext_vector_type(4))) short  s16x4;

__device__ __forceinline__ short f2bf(float f) {
    union { __hip_bfloat16 h; short s; } u;
    u.h = __float2bfloat16(f);
    return u.s;
}
__device__ __forceinline__ float bf2f(short s) {
    union { __hip_bfloat16 h; short s; } u;
    u.s = s;
    return __bfloat162float(u.h);
}
__device__ __forceinline__ float leaky(float x) { return x > 0.f ? x : 0.01f * x; }

__device__ __forceinline__ void split8(const f32x4& c0, const f32x4& c1,
                                       s16x8& h, s16x8& l) {
#pragma unroll
    for (int j = 0; j < 4; ++j) {
        short h0 = f2bf(c0[j]); h[j]     = h0; l[j]     = f2bf(c0[j] - bf2f(h0));
        short h1 = f2bf(c1[j]); h[4 + j] = h1; l[4 + j] = f2bf(c1[j] - bf2f(h1));
    }
}

// ---------------------------------------------------------------------------
// GEMM core: r13-exact. A on lgkmcnt (LDS), W sole vmcnt user, 2-kb lookahead,
// A-reuse x2 (BN=128). Caller decodes nb (0..31), ks (0..15).
// ---------------------------------------------------------------------------
__device__ __forceinline__ void gemm_core(const short* lhi, const short* llo,
                                          const float* __restrict__ W,
                                          float* __restrict__ outp,
                                          int tid, int nb, int ks)
{
    const int lane = tid & 63;
    const int wv   = tid >> 6;
    const int l15  = lane & 15;
    const int lk8  = lane >> 4;
    const int koff = ks * KSLICE;

    const int ncolA = nb * 128 + wv * 16 + l15;
    const int ncolB = ncolA + 64;
    const float* wpA = W + (size_t)ncolA * DIM + koff + lk8 * 8;
    const float* wpB = W + (size_t)ncolB * DIM + koff + lk8 * 8;

    f32x4 accA0 = {0.f,0.f,0.f,0.f}, accA1 = {0.f,0.f,0.f,0.f};
    f32x4 accA2 = {0.f,0.f,0.f,0.f}, accA3 = {0.f,0.f,0.f,0.f};
    f32x4 accB0 = {0.f,0.f,0.f,0.f}, accB1 = {0.f,0.f,0.f,0.f};
    f32x4 accB2 = {0.f,0.f,0.f,0.f}, accB3 = {0.f,0.f,0.f,0.f};

#define WLD(P, KB)                                                           \
    const f32x4 P##a0 = *(const f32x4*)(wpA + (KB)*64);                      \
    const f32x4 P##a1 = *(const f32x4*)(wpA + (KB)*64 + 4);                  \
    const f32x4 P##a2 = *(const f32x4*)(wpA + (KB)*64 + 32);                 \
    const f32x4 P##a3 = *(const f32x4*)(wpA + (KB)*64 + 36);                 \
    const f32x4 P##b0 = *(const f32x4*)(wpB + (KB)*64);                      \
    const f32x4 P##b1 = *(const f32x4*)(wpB + (KB)*64 + 4);                  \
    const f32x4 P##b2 = *(const f32x4*)(wpB + (KB)*64 + 32);                 \
    const f32x4 P##b3 = *(const f32x4*)(wpB + (KB)*64 + 36);

#define CKK(WA0, WA1, WB0, WB1, KB, KK)                                      \
    {   const int sl_ = (((KB)*8 + (KK)*4 + lk8) ^ (l15 & 7)) * 8;           \
        const s16x8 a0h = *(const s16x8*)&lhi[( 0 + l15)*256 + sl_];         \
        const s16x8 a1h = *(const s16x8*)&lhi[(16 + l15)*256 + sl_];         \
        const s16x8 a2h = *(const s16x8*)&lhi[(32 + l15)*256 + sl_];         \
        const s16x8 a3h = *(const s16x8*)&lhi[(48 + l15)*256 + sl_];         \
        const s16x8 a0l = *(const s16x8*)&llo[( 0 + l15)*256 + sl_];         \
        const s16x8 a1l = *(const s16x8*)&llo[(16 + l15)*256 + sl_];         \
        const s16x8 a2l = *(const s16x8*)&llo[(32 + l15)*256 + sl_];         \
        const s16x8 a3l = *(const s16x8*)&llo[(48 + l15)*256 + sl_];         \
        s16x8 bhA, blA, bhB, blB;                                            \
        split8(WA0, WA1, bhA, blA);                                          \
        split8(WB0, WB1, bhB, blB);                                          \
        accA0 = __builtin_amdgcn_mfma_f32_16x16x32_bf16(a0h, bhA, accA0, 0, 0, 0); \
        accA1 = __builtin_amdgcn_mfma_f32_16x16x32_bf16(a1h, bhA, accA1, 0, 0, 0); \
        accA2 = __builtin_amdgcn_mfma_f32_16x16x32_bf16(a2h, bhA, accA2, 0, 0, 0); \
        accA3 = __builtin_amdgcn_mfma_f32_16x16x32_bf16(a3h, bhA, accA3, 0, 0, 0); \
        accA0 = __builtin_amdgcn_mfma_f32_16x16x32_bf16(a0l, bhA, accA0, 0, 0, 0); \
        accA1 = __builtin_amdgcn_mfma_f32_16x16x32_bf16(a1l, bhA, accA1, 0, 0, 0); \
        accA2 = __builtin_amdgcn_mfma_f32_16x16x32_bf16(a2l, bhA, accA2, 0, 0, 0); \
        accA3 = __builtin_amdgcn_mfma_f32_16x16x32_bf16(a3l, bhA, accA3, 0, 0, 0); \
        accA0 = __builtin_amdgcn_mfma_f32_16x16x32_bf16(a0h, blA, accA0, 0, 0, 0); \
        accA1 = __builtin_amdgcn_mfma_f32_16x16x32_bf16(a1h, blA, accA1, 0, 0, 0); \
        accA2 = __builtin_amdgcn_mfma_f32_16x16x32_bf16(a2h, blA, accA2, 0, 0, 0); \
        accA3 = __builtin_amdgcn_mfma_f32_16x16x32_bf16(a3h, blA, accA3, 0, 0, 0); \
        accB0 = __builtin_amdgcn_mfma_f32_16x16x32_bf16(a0h, bhB, accB0, 0, 0, 0); \
        accB1 = __builtin_amdgcn_mfma_f32_16x16x32_bf16(a1h, bhB, accB1, 0, 0, 0); \
        accB2 = __builtin_amdgcn_mfma_f32_16x16x32_bf16(a2h, bhB, accB2, 0, 0, 0); \
        accB3 = __builtin_amdgcn_mfma_f32_16x16x32_bf16(a3h, bhB, accB3, 0, 0, 0); \
        accB0 = __builtin_amdgcn_mfma_f32_16x16x32_bf16(a0l, bhB, accB0, 0, 0, 0); \
        accB1 = __builtin_amdgcn_mfma_f32_16x16x32_bf16(a1l, bhB, accB1, 0, 0, 0); \
        accB2 = __builtin_amdgcn_mfma_f32_16x16x32_bf16(a2l, bhB, accB2, 0, 0, 0); \
        accB3 = __builtin_amdgcn_mfma_f32_16x16x32_bf16(a3l, bhB, accB3, 0, 0, 0); \
        accB0 = __builtin_amdgcn_mfma_f32_16x16x32_bf16(a0h, blB, accB0, 0, 0, 0); \
        accB1 = __builtin_amdgcn_mfma_f32_16x16x32_bf16(a1h, blB, accB1, 0, 0, 0); \
        accB2 = __builtin_amdgcn_mfma_f32_16x16x32_bf16(a2h, blB, accB2, 0, 0, 0); \
        accB3 = __builtin_amdgcn_mfma_f32_16x16x32_bf16(a3h, blB, accB3, 0, 0, 0); }

    WLD(w0_, 0) WLD(w1_, 1)
    CKK(w0_a0, w0_a1, w0_b0, w0_b1, 0, 0)
    CKK(w0_a2, w0_a3, w0_b2, w0_b3, 0, 1)
    WLD(w2_, 2)
    CKK(w1_a0, w1_a1, w1_b0, w1_b1, 1, 0)
    CKK(w1_a2, w1_a3, w1_b2, w1_b3, 1, 1)
    WLD(w3_, 3)
    CKK(w2_a0, w2_a1, w2_b0, w2_b1, 2, 0)
    CKK(w2_a2, w2_a3, w2_b2, w2_b3, 2, 1)
    CKK(w3_a0, w3_a1, w3_b0, w3_b1, 3, 0)
    CKK(w3_a2, w3_a3, w3_b2, w3_b3, 3, 1)

#undef WLD
#undef CKK

    float* op = outp + (size_t)ks * HSZ;
#pragma unroll
    for (int mt = 0; mt < 4; ++mt) {
        const f32x4 a = (mt == 0) ? accA0 : (mt == 1) ? accA1 : (mt == 2) ? accA2 : accA3;
        const f32x4 b = (mt == 0) ? accB0 : (mt == 1) ? accB1 : (mt == 2) ? accB2 : accB3;
#pragma unroll
        for (int r = 0; r < 4; ++r) {
            const int m = mt * 16 + lk8 * 4 + r;
            if (m < HROWS) {
                op[(size_t)m * DIM + ncolA] = a[r];
                op[(size_t)m * DIM + ncolB] = b[r];
            }
        }
    }
}

// ---------------------------------------------------------------------------
// staging helpers (write A slice into smem as bf16 hi/lo, swizzled)
// ---------------------------------------------------------------------------
__device__ __forceinline__ void stage_bf(char* smem, const short* Ah, const short* Al,
                                         int koff, int tid)
{
    short* lhi = (short*)smem;
    short* llo = (short*)(smem + 32768);
    for (int u = tid; u < 64 * 32; u += 256) {
        const int row  = u >> 5;
        const int c    = u & 31;
        const int slot = c ^ (row & 7);
        *(s16x8*)&lhi[row * 256 + slot * 8] =
            *(const s16x8*)(Ah + (size_t)row * DIM + koff + c * 8);
        *(s16x8*)&llo[row * 256 + slot * 8] =
            *(const s16x8*)(Al + (size_t)row * DIM + koff + c * 8);
    }
}

__device__ __forceinline__ void stage_f32(char* smem, const float* Asrc,
                                          int koff, int tid)
{
    short* lhi = (short*)smem;
    short* llo = (short*)(smem + 32768);
    for (int u = tid; u < 64 * 32; u += 256) {
        const int row  = u >> 5;
        const int c    = u & 31;
        const int slot = c ^ (row & 7);
        f32x4 a0 = {0.f,0.f,0.f,0.f}, a1 = {0.f,0.f,0.f,0.f};
        if (row < HROWS) {
            const float* g = Asrc + (size_t)row * DIM + koff + c * 8;
            a0 = *(const f32x4*)g;
            a1 = *(const f32x4*)(g + 4);
        }
        s16x8 vh, vl; split8(a0, a1, vh, vl);
        *(s16x8*)&lhi[row * 256 + slot * 8] = vh;
        *(s16x8*)&llo[row * 256 + slot * 8] = vl;
    }
}

// ---------------------------------------------------------------------------
// p2 tail: winner of nb group reduces its 128 columns -> bf16 hi/lo of h,
// plus per-nb attention-dot partials dotp2[nb][54][6].
// ---------------------------------------------------------------------------
__device__ void p2_tail(int nb, int tid, char* smem,
                        const float* __restrict__ hpart,
                        const float* __restrict__ wA, const float* __restrict__ wB,
                        const float* __restrict__ wC,
                        short* __restrict__ hbh, short* __restrict__ hbl,
                        float* __restrict__ dotp2)
{
    float* hs = (float*)smem;    // [54][128]
    for (int x = tid; x < HROWS * 32; x += 256) {
        const int row = x >> 5, q = x & 31;
        const int col = nb * 128 + q * 4;
        f32x4 s = {0.f,0.f,0.f,0.f};
#pragma unroll
        for (int sl = 0; sl < SPLITK; ++sl)
            s += *(const f32x4*)(hpart + (size_t)sl * HSZ + (size_t)row * DIM + col);
        *(f32x4*)&hs[row * 128 + q * 4] = s;
        s16x4 vh, vl;
#pragma unroll
        for (int j = 0; j < 4; ++j) {
            const short h = f2bf(s[j]);
            vh[j] = h; vl[j] = f2bf(s[j] - bf2f(h));
        }
        *(s16x4*)&hbh[(size_t)row * DIM + col] = vh;
        *(s16x4*)&hbl[(size_t)row * DIM + col] = vl;
    }
    __syncthreads();
    for (int x = tid; x < 324; x += 256) {
        const int r = x / 6, v = x % 6;
        const float* wv = (v < 2 ? wA : v < 4 ? wB : wC) + (v & 1) * DIM + nb * 128;
        float s = 0.f;
#pragma unroll 8
        for (int c = 0; c < 128; ++c) s += hs[r * 128 + c] * wv[c];
        dotp2[(size_t)nb * 324 + x] = s;
    }
}

// ---------------------------------------------------------------------------
// p45 tail: winner of pair-group g (cols g*128..+127 and +2048 partners).
// T-build from dotp2, then 2 chunks of 64 pairs: reduce gs, applyT+rope.
// ---------------------------------------------------------------------------
__device__ void p45_tail(int g, int tid, char* smem,
                         const float* __restrict__ hpart,
                         const float* __restrict__ dotp2,
                         const float* __restrict__ edge,
                         short* __restrict__ xh, short* __restrict__ xl,
                         float* __restrict__ xo, int last)
{
    float* gs  = (float*)smem;                    // [54][128]
    float* TsP = (float*)(smem + 27648);          // [54][54]
    float* dsP = (float*)(smem + 27648 + 11664);  // [324]
    __shared__ float ad0[5], adc[12], ar[6], fdot3[12], fdot5[12], ddot5[5];
    constexpr int PF[12] = {0,0,0,1,1,2,2,2,3,3,4,4};

    // ---- T build ----
    for (int x = tid; x < 324; x += 256) {
        float s = 0.f;
#pragma unroll
        for (int nb = 0; nb < 32; ++nb) s += dotp2[(size_t)nb * 324 + x];
        dsP[x] = s;
    }
    for (int i = tid; i < 54 * 54; i += 256) TsP[i] = 0.f;
    __syncthreads();

    if (tid < 12) {                       // level if
        const int p = tid;
        const float u = dsP[(6+p)*6 + 0];
        const float ss = leaky(u + dsP[(6+p)*6 + 1]);
        float sc[3], mx = ss;
#pragma unroll
        for (int j = 0; j < 3; ++j) { sc[j] = leaky(u + dsP[(18+3*p+j)*6 + 1]); mx = fmaxf(mx, sc[j]); }
        float e0 = expf(ss - mx), s = e0, ec[3];
#pragma unroll
        for (int j = 0; j < 3; ++j) { ec[j] = expf(sc[j] - mx); s += ec[j]; }
        const float inv = 1.f / s;
        const float a0 = e0 * inv;
        float f3 = a0 * dsP[(6+p)*6 + 3];
        float f5 = a0 * dsP[(6+p)*6 + 5];
        TsP[(6+p)*54 + 6+p] = a0;
#pragma unroll
        for (int j = 0; j < 3; ++j) {
            const float a = ec[j] * inv;
            TsP[(6+p)*54 + 18+3*p+j] = a;
            f3 += a * dsP[(18+3*p+j)*6 + 3];
            f5 += a * dsP[(18+3*p+j)*6 + 5];
        }
        fdot3[p] = f3; fdot5[p] = f5;
    }
    __syncthreads();

    if (tid < 5) {                        // level fd
        const int p = tid;
        const int cstart[5] = {0,3,5,8,10};
        const int ccnt[5]   = {3,2,3,2,2};
        const float u = dsP[(1+p)*6 + 2];
        const float ss = leaky(u + dsP[(1+p)*6 + 3]);
        const int n = ccnt[p], c0 = cstart[p];
        float mx = ss, sc[3];
        for (int j = 0; j < n; ++j) { sc[j] = leaky(u + fdot3[c0+j]); mx = fmaxf(mx, sc[j]); }
        float e0 = expf(ss - mx), s = e0, ec[3];
        for (int j = 0; j < n; ++j) { ec[j] = expf(sc[j] - mx); s += ec[j]; }
        const float inv = 1.f / s;
        ad0[p] = e0 * inv;
        float d5 = ad0[p] * dsP[(1+p)*6 + 5];
        for (int j = 0; j < n; ++j) {
            const float a = ec[j] * inv;
            adc[c0+j] = a;
            d5 += a * fdot5[c0+j];
        }
        ddot5[p] = d5;
    }
    __syncthreads();

    if (tid == 0) {                       // level dr
        const float u = dsP[0*6 + 4];
        const float ss = leaky(u + dsP[0*6 + 5]);
        float mx = ss, sc[5];
#pragma unroll
        for (int d = 0; d < 5; ++d) { sc[d] = leaky(u + ddot5[d]); mx = fmaxf(mx, sc[d]); }
        float e0 = expf(ss - mx), s = e0, ec[5];
#pragma unroll
        for (int d = 0; d < 5; ++d) { ec[d] = expf(sc[d] - mx); s += ec[d]; }
        const float inv = 1.f / s;
        ar[0] = e0 * inv;
#pragma unroll
        for (int d = 0; d < 5; ++d) ar[1+d] = ec[d] * inv;
    }
    for (int q = tid; q < 36; q += 256) TsP[(18+q)*54 + 18+q] = 1.f;
    __syncthreads();

    if (tid < 54) {                       // domain rows
        const int j = tid;
        const int cstart[5] = {0,3,5,8,10};
        const int ccnt[5]   = {3,2,3,2,2};
        for (int p = 0; p < 5; ++p) {
            float t = ad0[p] * ((j == 1+p) ? 1.f : 0.f);
            for (int c = cstart[p]; c < cstart[p] + ccnt[p]; ++c) t += adc[c] * TsP[(6+c)*54 + j];
            TsP[(1+p)*54 + j] = t;
        }
    }
    __syncthreads();
    if (tid < 54) {                       // root row
        float t = ar[0] * ((tid == 0) ? 1.f : 0.f);
        for (int d = 0; d < 5; ++d) t += ar[1+d] * TsP[(1+d)*54 + tid];
        TsP[0*54 + tid] = t;
    }
    __syncthreads();

    // ---- 2 chunks of 64 pairs: gs reduce, then applyT + rope ----
    for (int cc = 0; cc < 2; ++cc) {
        for (int x = tid; x < HROWS * 32; x += 256) {
            const int row = x >> 5, q = x & 31;
            const int side = q >> 4, qi = q & 15;
            const int col = g * 128 + cc * 64 + qi * 4 + side * 2048;
            f32x4 s = {0.f,0.f,0.f,0.f};
#pragma unroll
            for (int sl = 0; sl < SPLITK; ++sl)
                s += *(const f32x4*)(hpart + (size_t)sl * HSZ + (size_t)row * DIM + col);
            *(f32x4*)&gs[row * 128 + side * 64 + qi * 4] = s;
        }
        __syncthreads();

        const int p  = tid & 63;
        const int rq = tid >> 6;             // 0..3
        const int j  = g * 128 + cc * 64 + p;
        const int jj = j + 2048;
        const float e0v = edge[j], e1v = edge[2048 + j], e2v = edge[4096 + j];
        const float er0 = cosf(e0v), ei0 = sinf(e0v);
        const float er1 = cosf(e1v), ei1 = sinf(e1v);
        const float er2 = cosf(e2v), ei2 = sinf(e2v);

        float a0r = 0.f, a0i = 0.f;
#pragma unroll 6
        for (int k = 0; k < HROWS; ++k) {
            const float t0 = TsP[k];
            a0r += t0 * gs[k * 128 + p];
            a0i += t0 * gs[k * 128 + 64 + p];
        }
        const float rr = a0r, ri = a0i;

        for (int r = rq; r < HROWS; r += 4) {
            float vr, vi, scale;
            if (r == 0) {
                vr = rr; vi = ri; scale = 1.f;
            } else {
                int row1, row2 = 0;
                if (r < 6)       { row1 = r; }
                else if (r < 18) { const int c = r - 6;      row1 = 1 + PF[c]; row2 = r; }
                else             { const int c = (r - 18)/3; row1 = 1 + PF[c]; row2 = 6 + c; }

                float a1r = 0.f, a1i = 0.f;
#pragma unroll 6
                for (int k = 0; k < HROWS; ++k) {
                    const float t1 = TsP[row1 * 54 + k];
                    a1r += t1 * gs[k * 128 + p];
                    a1i += t1 * gs[k * 128 + 64 + p];
                }
                const float dr = a1r + rr * er0 - ri * ei0;
                const float di = a1i + rr * ei0 + ri * er0;
                if (r < 6) {
                    vr = dr; vi = di; scale = 0.5f;
                } else {
                    float a2r = 0.f, a2i = 0.f;
#pragma unroll 6
                    for (int k = 0; k < HROWS; ++k) {
                        const float t2 = TsP[row2 * 54 + k];
                        a2r += t2 * gs[k * 128 + p];
                        a2i += t2 * gs[k * 128 + 64 + p];
                    }
                    const float fr = a2r + dr * er1 - di * ei1;
                    const float fi = a2i + dr * ei1 + di * er1;
                    if (r < 18) {
                        vr = fr; vi = fi; scale = 1.f / 3.f;
                    } else {
                        vr = gs[r * 128 + p]      + fr * er2 - fi * ei2;
                        vi = gs[r * 128 + 64 + p] + fr * ei2 + fi * er2;
                        scale = 0.25f;
                    }
                }
            }
            vr *= scale; vi *= scale;
            if (last) {
                xo[(size_t)r * DIM + j]  = vr;
                xo[(size_t)r * DIM + jj] = vi;
            } else {
                const short h0 = f2bf(vr);
                xh[(size_t)r * DIM + j] = h0;
                xl[(size_t)r * DIM + j] = f2bf(vr - bf2f(h0));
                const short h1 = f2bf(vi);
                xh[(size_t)r * DIM + jj] = h1;
                xl[(size_t)r * DIM + jj] = f2bf(vi - bf2f(h1));
            }
        }
        __syncthreads();
    }
}

// ---------------------------------------------------------------------------
// Kernel A: gemm1 (+ p2 tail by the last block of each nb group).
// ---------------------------------------------------------------------------
__global__ __launch_bounds__(256) void gemm1_bf_g(const short* __restrict__ Ah,
                                                  const short* __restrict__ Al,
                                                  const float* __restrict__ W,
                                                  float* __restrict__ hpart,
                                                  const float* __restrict__ wA,
                                                  const float* __restrict__ wB,
                                                  const float* __restrict__ wC,
                                                  short* __restrict__ hbh,
                                                  short* __restrict__ hbl,
                                                  float* __restrict__ dotp2,
                                                  int* __restrict__ tickets)
{
    __shared__ char smem[65536];
    __shared__ int winflag;
    const int tid = threadIdx.x;
    const int bid = blockIdx.x;
    const int swz = (bid & 7) * 64 + (bid >> 3);
    const int nb  = swz & 31;
    const int ks  = swz >> 5;

    stage_bf(smem, Ah, Al, ks * KSLICE, tid);
    __syncthreads();
    gemm_core((const short*)smem, (const short*)(smem + 32768), W, hpart, tid, nb, ks);

    __threadfence();
    if (tid == 0) winflag = (atomicAdd(&tickets[nb], 1) == SPLITK - 1) ? 1 : 0;
    __syncthreads();
    if (!winflag) return;
    __threadfence();
    p2_tail(nb, tid, smem, hpart, wA, wB, wC, hbh, hbl, dotp2);
    if (tid == 0) tickets[nb] = 0;
}

__global__ __launch_bounds__(256) void gemm1_f32_g(const float* __restrict__ Asrc,
                                                   const float* __restrict__ W,
                                                   float* __restrict__ hpart,
                                                   const float* __restrict__ wA,
                                                   const float* __restrict__ wB,
                                                   const float* __restrict__ wC,
                                                   short* __restrict__ hbh,
                                                   short* __restrict__ hbl,
                                                   float* __restrict__ dotp2,
                                                   int* __restrict__ tickets)
{
    __shared__ char smem[65536];
    __shared__ int winflag;
    const int tid = threadIdx.x;
    const int bid = blockIdx.x;
    const int swz = (bid & 7) * 64 + (bid >> 3);
    const int nb  = swz & 31;
    const int ks  = swz >> 5;

    stage_f32(smem, Asrc, ks * KSLICE, tid);
    __syncthreads();
    gemm_core((const short*)smem, (const short*)(smem + 32768), W, hpart, tid, nb, ks);

    __threadfence();
    if (tid == 0) winflag = (atomicAdd(&tickets[nb], 1) == SPLITK - 1) ? 1 : 0;
    __syncthreads();
    if (!winflag) return;
    __threadfence();
    p2_tail(nb, tid, smem, hpart, wA, wB, wC, hbh, hbl, dotp2);
    if (tid == 0) tickets[nb] = 0;
}

// ---------------------------------------------------------------------------
// Kernel B: gemm2 (+ p45 tail by the last block of each pair-group g = nb&15).
// ---------------------------------------------------------------------------
__global__ __launch_bounds__(256) void gemm2_g(const short* __restrict__ Ah,
                                               const short* __restrict__ Al,
                                               const float* __restrict__ W,
                                               float* __restrict__ hpart,
                                               const float* __restrict__ dotp2,
                                               const float* __restrict__ edge,
                                               short* __restrict__ xh,
                                               short* __restrict__ xl,
                                               float* __restrict__ xo, int last,
                                               int* __restrict__ tickets)
{
    __shared__ char smem[65536];
    __shared__ int winflag;
    const int tid = threadIdx.x;
    const int bid = blockIdx.x;
    const int swz = (bid & 7) * 64 + (bid >> 3);
    const int nb  = swz & 31;
    const int ks  = swz >> 5;
    const int g   = nb & 15;

    stage_bf(smem, Ah, Al, ks * KSLICE, tid);
    __syncthreads();
    gemm_core((const short*)smem, (const short*)(smem + 32768), W, hpart, tid, nb, ks);

    __threadfence();
    if (tid == 0) winflag = (atomicAdd(&tickets[g], 1) == 2 * SPLITK - 1) ? 1 : 0;
    __syncthreads();
    if (!winflag) return;
    __threadfence();
    p45_tail(g, tid, smem, hpart, dotp2, edge, xh, xl, xo, last);
    if (tid == 0) tickets[g] = 0;
}

// ---------------------------------------------------------------------------
extern "C" void kernel_launch(void* const* d_in, const int* in_sizes, int n_in,
                              void* d_out, int out_size, void* d_ws, size_t ws_size,
                              hipStream_t stream)
{
    const float* ce    = (const float*)d_in[0];
    const float* gatW  = (const float*)d_in[1];
    const float* attif = (const float*)d_in[2];
    const float* attfd = (const float*)d_in[3];
    const float* attdr = (const float*)d_in[4];
    const float* metaW = (const float*)d_in[5];
    const float* edge  = (const float*)d_in[6];
    float* out = (float*)d_out;

    char* w = (char*)d_ws;
    float* hpart = (float*)w;   w += (size_t)SPLITK * HSZ * 4;   // 14.2 MB
    float* dotp2 = (float*)w;   w += 32 * 324 * 4;               // 41.5 KB
    short* xbfh  = (short*)w;   w += (size_t)64 * DIM * 2;       // 512 KB each
    short* xbfl  = (short*)w;   w += (size_t)64 * DIM * 2;
    short* hbfh  = (short*)w;   w += (size_t)64 * DIM * 2;
    short* hbfl  = (short*)w;   w += (size_t)64 * DIM * 2;
    int*   tickA = (int*)w;     w += 32 * 4;
    int*   tickB = (int*)w;     w += 16 * 4;

    hipMemsetAsync(tickA, 0, 48 * sizeof(int), stream);

    for (int i = 0; i < 4; ++i) {
        const float* wif = attif + (size_t)i * 2 * DIM;
        const float* wfd = attfd + (size_t)i * 2 * DIM;
        const float* wdr = attdr + (size_t)i * 2 * DIM;
        if (i == 0)
            hipLaunchKernelGGL(gemm1_f32_g, dim3(512), dim3(256), 0, stream,
                               ce, gatW, hpart, wif, wfd, wdr, hbfh, hbfl, dotp2, tickA);
        else
            hipLaunchKernelGGL(gemm1_bf_g, dim3(512), dim3(256), 0, stream,
                               xbfh, xbfl, gatW + (size_t)i * DIM * DIM, hpart,
                               wif, wfd, wdr, hbfh, hbfl, dotp2, tickA);
        hipLaunchKernelGGL(gemm2_g, dim3(512), dim3(256), 0, stream,
                           hbfh, hbfl, metaW + (size_t)i * DIM * DIM, hpart,
                           dotp2, edge, xbfh, xbfl, out, (i == 3) ? 1 : 0, tickB);
    }
}

// Round 17
// 1109.298 us; speedup vs baseline: 1.0122x; 1.0122x over previous
//
#include <hip/hip_runtime.h>
#include <hip/hip_bf16.h>

#define DIM 4096
#define HROWS 54
#define HSZ (54 * 4096)
#define SPLITK 16
#define KSLICE 256

typedef __attribute__((ext_vector_type(4))) float  f32x4;
typedef __attribute__((ext_vector_type(8))) short  s16x8;
typedef __attribute__((ext_vector_type(4))) short  s16x4;

__device__ __forceinline__ short f2bf(float f) {
    union { __hip_bfloat16 h; short s; } u;
    u.h = __float2bfloat16(f);
    return u.s;
}
__device__ __forceinline__ float bf2f(short s) {
    union { __hip_bfloat16 h; short s; } u;
    u.s = s;
    return __bfloat162float(u.h);
}
__device__ __forceinline__ float leaky(float x) { return x > 0.f ? x : 0.01f * x; }

__device__ __forceinline__ void split8(const f32x4& c0, const f32x4& c1,
                                       s16x8& h, s16x8& l) {
#pragma unroll
    for (int j = 0; j < 4; ++j) {
        short h0 = f2bf(c0[j]); h[j]     = h0; l[j]     = f2bf(c0[j] - bf2f(h0));
        short h1 = f2bf(c1[j]); h[4 + j] = h1; l[4 + j] = f2bf(c1[j] - bf2f(h1));
    }
}

// LDS overlay: typed union, direct member access everywhere (keeps
// addrspace(3) inference -> ds_read/ds_write, never flat).
union SmemU {
    struct { short lhi[64 * 256]; short llo[64 * 256]; } g;   // 64 KB (gemm)
    float hs[HROWS * 128];                                    // 27 KB (p2 tail)
    struct { float gs[HROWS * 128]; float Ts[54 * 54]; float ds[324]; } t; // 40 KB
};

// ---------------------------------------------------------------------------
// GEMM core: r13-exact. A on lgkmcnt (LDS), W sole vmcnt user, 2-kb lookahead,
// A-reuse x2 (BN=128). Caller decodes nb (0..31), ks (0..15).
// ---------------------------------------------------------------------------
__device__ __forceinline__ void gemm_core(const short* lhi, const short* llo,
                                          const float* __restrict__ W,
                                          float* __restrict__ outp,
                                          int tid, int nb, int ks)
{
    const int lane = tid & 63;
    const int wv   = tid >> 6;
    const int l15  = lane & 15;
    const int lk8  = lane >> 4;
    const int koff = ks * KSLICE;

    const int ncolA = nb * 128 + wv * 16 + l15;
    const int ncolB = ncolA + 64;
    const float* wpA = W + (size_t)ncolA * DIM + koff + lk8 * 8;
    const float* wpB = W + (size_t)ncolB * DIM + koff + lk8 * 8;

    f32x4 accA0 = {0.f,0.f,0.f,0.f}, accA1 = {0.f,0.f,0.f,0.f};
    f32x4 accA2 = {0.f,0.f,0.f,0.f}, accA3 = {0.f,0.f,0.f,0.f};
    f32x4 accB0 = {0.f,0.f,0.f,0.f}, accB1 = {0.f,0.f,0.f,0.f};
    f32x4 accB2 = {0.f,0.f,0.f,0.f}, accB3 = {0.f,0.f,0.f,0.f};

#define WLD(P, KB)                                                           \
    const f32x4 P##a0 = *(const f32x4*)(wpA + (KB)*64);                      \
    const f32x4 P##a1 = *(const f32x4*)(wpA + (KB)*64 + 4);                  \
    const f32x4 P##a2 = *(const f32x4*)(wpA + (KB)*64 + 32);                 \
    const f32x4 P##a3 = *(const f32x4*)(wpA + (KB)*64 + 36);                 \
    const f32x4 P##b0 = *(const f32x4*)(wpB + (KB)*64);                      \
    const f32x4 P##b1 = *(const f32x4*)(wpB + (KB)*64 + 4);                  \
    const f32x4 P##b2 = *(const f32x4*)(wpB + (KB)*64 + 32);                 \
    const f32x4 P##b3 = *(const f32x4*)(wpB + (KB)*64 + 36);

#define CKK(WA0, WA1, WB0, WB1, KB, KK)                                      \
    {   const int sl_ = (((KB)*8 + (KK)*4 + lk8) ^ (l15 & 7)) * 8;           \
        const s16x8 a0h = *(const s16x8*)&lhi[( 0 + l15)*256 + sl_];         \
        const s16x8 a1h = *(const s16x8*)&lhi[(16 + l15)*256 + sl_];         \
        const s16x8 a2h = *(const s16x8*)&lhi[(32 + l15)*256 + sl_];         \
        const s16x8 a3h = *(const s16x8*)&lhi[(48 + l15)*256 + sl_];         \
        const s16x8 a0l = *(const s16x8*)&llo[( 0 + l15)*256 + sl_];         \
        const s16x8 a1l = *(const s16x8*)&llo[(16 + l15)*256 + sl_];         \
        const s16x8 a2l = *(const s16x8*)&llo[(32 + l15)*256 + sl_];         \
        const s16x8 a3l = *(const s16x8*)&llo[(48 + l15)*256 + sl_];         \
        s16x8 bhA, blA, bhB, blB;                                            \
        split8(WA0, WA1, bhA, blA);                                          \
        split8(WB0, WB1, bhB, blB);                                          \
        accA0 = __builtin_amdgcn_mfma_f32_16x16x32_bf16(a0h, bhA, accA0, 0, 0, 0); \
        accA1 = __builtin_amdgcn_mfma_f32_16x16x32_bf16(a1h, bhA, accA1, 0, 0, 0); \
        accA2 = __builtin_amdgcn_mfma_f32_16x16x32_bf16(a2h, bhA, accA2, 0, 0, 0); \
        accA3 = __builtin_amdgcn_mfma_f32_16x16x32_bf16(a3h, bhA, accA3, 0, 0, 0); \
        accA0 = __builtin_amdgcn_mfma_f32_16x16x32_bf16(a0l, bhA, accA0, 0, 0, 0); \
        accA1 = __builtin_amdgcn_mfma_f32_16x16x32_bf16(a1l, bhA, accA1, 0, 0, 0); \
        accA2 = __builtin_amdgcn_mfma_f32_16x16x32_bf16(a2l, bhA, accA2, 0, 0, 0); \
        accA3 = __builtin_amdgcn_mfma_f32_16x16x32_bf16(a3l, bhA, accA3, 0, 0, 0); \
        accA0 = __builtin_amdgcn_mfma_f32_16x16x32_bf16(a0h, blA, accA0, 0, 0, 0); \
        accA1 = __builtin_amdgcn_mfma_f32_16x16x32_bf16(a1h, blA, accA1, 0, 0, 0); \
        accA2 = __builtin_amdgcn_mfma_f32_16x16x32_bf16(a2h, blA, accA2, 0, 0, 0); \
        accA3 = __builtin_amdgcn_mfma_f32_16x16x32_bf16(a3h, blA, accA3, 0, 0, 0); \
        accB0 = __builtin_amdgcn_mfma_f32_16x16x32_bf16(a0h, bhB, accB0, 0, 0, 0); \
        accB1 = __builtin_amdgcn_mfma_f32_16x16x32_bf16(a1h, bhB, accB1, 0, 0, 0); \
        accB2 = __builtin_amdgcn_mfma_f32_16x16x32_bf16(a2h, bhB, accB2, 0, 0, 0); \
        accB3 = __builtin_amdgcn_mfma_f32_16x16x32_bf16(a3h, bhB, accB3, 0, 0, 0); \
        accB0 = __builtin_amdgcn_mfma_f32_16x16x32_bf16(a0l, bhB, accB0, 0, 0, 0); \
        accB1 = __builtin_amdgcn_mfma_f32_16x16x32_bf16(a1l, bhB, accB1, 0, 0, 0); \
        accB2 = __builtin_amdgcn_mfma_f32_16x16x32_bf16(a2l, bhB, accB2, 0, 0, 0); \
        accB3 = __builtin_amdgcn_mfma_f32_16x16x32_bf16(a3l, bhB, accB3, 0, 0, 0); \
        accB0 = __builtin_amdgcn_mfma_f32_16x16x32_bf16(a0h, blB, accB0, 0, 0, 0); \
        accB1 = __builtin_amdgcn_mfma_f32_16x16x32_bf16(a1h, blB, accB1, 0, 0, 0); \
        accB2 = __builtin_amdgcn_mfma_f32_16x16x32_bf16(a2h, blB, accB2, 0, 0, 0); \
        accB3 = __builtin_amdgcn_mfma_f32_16x16x32_bf16(a3h, blB, accB3, 0, 0, 0); }

    WLD(w0_, 0) WLD(w1_, 1)
    CKK(w0_a0, w0_a1, w0_b0, w0_b1, 0, 0)
    CKK(w0_a2, w0_a3, w0_b2, w0_b3, 0, 1)
    WLD(w2_, 2)
    CKK(w1_a0, w1_a1, w1_b0, w1_b1, 1, 0)
    CKK(w1_a2, w1_a3, w1_b2, w1_b3, 1, 1)
    WLD(w3_, 3)
    CKK(w2_a0, w2_a1, w2_b0, w2_b1, 2, 0)
    CKK(w2_a2, w2_a3, w2_b2, w2_b3, 2, 1)
    CKK(w3_a0, w3_a1, w3_b0, w3_b1, 3, 0)
    CKK(w3_a2, w3_a3, w3_b2, w3_b3, 3, 1)

#undef WLD
#undef CKK

    float* op = outp + (size_t)ks * HSZ;
#pragma unroll
    for (int mt = 0; mt < 4; ++mt) {
        const f32x4 a = (mt == 0) ? accA0 : (mt == 1) ? accA1 : (mt == 2) ? accA2 : accA3;
        const f32x4 b = (mt == 0) ? accB0 : (mt == 1) ? accB1 : (mt == 2) ? accB2 : accB3;
#pragma unroll
        for (int r = 0; r < 4; ++r) {
            const int m = mt * 16 + lk8 * 4 + r;
            if (m < HROWS) {
                op[(size_t)m * DIM + ncolA] = a[r];
                op[(size_t)m * DIM + ncolB] = b[r];
            }
        }
    }
}

// ---------------------------------------------------------------------------
// staging helpers — typed array references, forceinline (addrspace-safe)
// ---------------------------------------------------------------------------
__device__ __forceinline__ void stage_bf(short (&lhi)[64*256], short (&llo)[64*256],
                                         const short* Ah, const short* Al,
                                         int koff, int tid)
{
    for (int u = tid; u < 64 * 32; u += 256) {
        const int row  = u >> 5;
        const int c    = u & 31;
        const int slot = c ^ (row & 7);
        *(s16x8*)&lhi[row * 256 + slot * 8] =
            *(const s16x8*)(Ah + (size_t)row * DIM + koff + c * 8);
        *(s16x8*)&llo[row * 256 + slot * 8] =
            *(const s16x8*)(Al + (size_t)row * DIM + koff + c * 8);
    }
}

__device__ __forceinline__ void stage_f32(short (&lhi)[64*256], short (&llo)[64*256],
                                          const float* Asrc, int koff, int tid)
{
    for (int u = tid; u < 64 * 32; u += 256) {
        const int row  = u >> 5;
        const int c    = u & 31;
        const int slot = c ^ (row & 7);
        f32x4 a0 = {0.f,0.f,0.f,0.f}, a1 = {0.f,0.f,0.f,0.f};
        if (row < HROWS) {
            const float* g = Asrc + (size_t)row * DIM + koff + c * 8;
            a0 = *(const f32x4*)g;
            a1 = *(const f32x4*)(g + 4);
        }
        s16x8 vh, vl; split8(a0, a1, vh, vl);
        *(s16x8*)&lhi[row * 256 + slot * 8] = vh;
        *(s16x8*)&llo[row * 256 + slot * 8] = vl;
    }
}

// ---------------------------------------------------------------------------
// p2 tail (winner of nb group): reduce 128 cols -> bf16 hi/lo h + dot partials
// ---------------------------------------------------------------------------
__device__ __forceinline__ void p2_tail(int nb, int tid, float (&hs)[HROWS*128],
                                        const float* __restrict__ hpart,
                                        const float* __restrict__ wA,
                                        const float* __restrict__ wB,
                                        const float* __restrict__ wC,
                                        short* __restrict__ hbh, short* __restrict__ hbl,
                                        float* __restrict__ dotp2)
{
    for (int x = tid; x < HROWS * 32; x += 256) {
        const int row = x >> 5, q = x & 31;
        const int col = nb * 128 + q * 4;
        f32x4 s = {0.f,0.f,0.f,0.f};
#pragma unroll
        for (int sl = 0; sl < SPLITK; ++sl)
            s += *(const f32x4*)(hpart + (size_t)sl * HSZ + (size_t)row * DIM + col);
        *(f32x4*)&hs[row * 128 + q * 4] = s;
        s16x4 vh, vl;
#pragma unroll
        for (int j = 0; j < 4; ++j) {
            const short h = f2bf(s[j]);
            vh[j] = h; vl[j] = f2bf(s[j] - bf2f(h));
        }
        *(s16x4*)&hbh[(size_t)row * DIM + col] = vh;
        *(s16x4*)&hbl[(size_t)row * DIM + col] = vl;
    }
    __syncthreads();
    for (int x = tid; x < 324; x += 256) {
        const int r = x / 6, v = x % 6;
        const float* wv = (v < 2 ? wA : v < 4 ? wB : wC) + (v & 1) * DIM + nb * 128;
        float s = 0.f;
#pragma unroll 8
        for (int c = 0; c < 128; ++c) s += hs[r * 128 + c] * wv[c];
        dotp2[(size_t)nb * 324 + x] = s;
    }
}

// ---------------------------------------------------------------------------
// p45 tail (winner of pair-group g): T-build, then 2 chunks of 64 pairs.
// ---------------------------------------------------------------------------
__device__ __forceinline__ void p45_tail(int g, int tid,
                                         float (&gs)[HROWS*128], float (&Ts)[54*54],
                                         float (&ds)[324],
                                         const float* __restrict__ hpart,
                                         const float* __restrict__ dotp2,
                                         const float* __restrict__ edge,
                                         short* __restrict__ xh, short* __restrict__ xl,
                                         float* __restrict__ xo, int last)
{
    __shared__ float ad0[5], adc[12], ar[6], fdot3[12], fdot5[12], ddot5[5];
    constexpr int PF[12] = {0,0,0,1,1,2,2,2,3,3,4,4};

    for (int x = tid; x < 324; x += 256) {
        float s = 0.f;
#pragma unroll
        for (int nb = 0; nb < 32; ++nb) s += dotp2[(size_t)nb * 324 + x];
        ds[x] = s;
    }
    for (int i = tid; i < 54 * 54; i += 256) Ts[i] = 0.f;
    __syncthreads();

    if (tid < 12) {                       // level if
        const int p = tid;
        const float u = ds[(6+p)*6 + 0];
        const float ss = leaky(u + ds[(6+p)*6 + 1]);
        float sc[3], mx = ss;
#pragma unroll
        for (int j = 0; j < 3; ++j) { sc[j] = leaky(u + ds[(18+3*p+j)*6 + 1]); mx = fmaxf(mx, sc[j]); }
        float e0 = expf(ss - mx), s = e0, ec[3];
#pragma unroll
        for (int j = 0; j < 3; ++j) { ec[j] = expf(sc[j] - mx); s += ec[j]; }
        const float inv = 1.f / s;
        const float a0 = e0 * inv;
        float f3 = a0 * ds[(6+p)*6 + 3];
        float f5 = a0 * ds[(6+p)*6 + 5];
        Ts[(6+p)*54 + 6+p] = a0;
#pragma unroll
        for (int j = 0; j < 3; ++j) {
            const float a = ec[j] * inv;
            Ts[(6+p)*54 + 18+3*p+j] = a;
            f3 += a * ds[(18+3*p+j)*6 + 3];
            f5 += a * ds[(18+3*p+j)*6 + 5];
        }
        fdot3[p] = f3; fdot5[p] = f5;
    }
    __syncthreads();

    if (tid < 5) {                        // level fd
        const int p = tid;
        const int cstart[5] = {0,3,5,8,10};
        const int ccnt[5]   = {3,2,3,2,2};
        const float u = ds[(1+p)*6 + 2];
        const float ss = leaky(u + ds[(1+p)*6 + 3]);
        const int n = ccnt[p], c0 = cstart[p];
        float mx = ss, sc[3];
        for (int j = 0; j < n; ++j) { sc[j] = leaky(u + fdot3[c0+j]); mx = fmaxf(mx, sc[j]); }
        float e0 = expf(ss - mx), s = e0, ec[3];
        for (int j = 0; j < n; ++j) { ec[j] = expf(sc[j] - mx); s += ec[j]; }
        const float inv = 1.f / s;
        ad0[p] = e0 * inv;
        float d5 = ad0[p] * ds[(1+p)*6 + 5];
        for (int j = 0; j < n; ++j) {
            const float a = ec[j] * inv;
            adc[c0+j] = a;
            d5 += a * fdot5[c0+j];
        }
        ddot5[p] = d5;
    }
    __syncthreads();

    if (tid == 0) {                       // level dr
        const float u = ds[0*6 + 4];
        const float ss = leaky(u + ds[0*6 + 5]);
        float mx = ss, sc[5];
#pragma unroll
        for (int d = 0; d < 5; ++d) { sc[d] = leaky(u + ddot5[d]); mx = fmaxf(mx, sc[d]); }
        float e0 = expf(ss - mx), s = e0, ec[5];
#pragma unroll
        for (int d = 0; d < 5; ++d) { ec[d] = expf(sc[d] - mx); s += ec[d]; }
        const float inv = 1.f / s;
        ar[0] = e0 * inv;
#pragma unroll
        for (int d = 0; d < 5; ++d) ar[1+d] = ec[d] * inv;
    }
    for (int q = tid; q < 36; q += 256) Ts[(18+q)*54 + 18+q] = 1.f;
    __syncthreads();

    if (tid < 54) {                       // domain rows
        const int j = tid;
        const int cstart[5] = {0,3,5,8,10};
        const int ccnt[5]   = {3,2,3,2,2};
        for (int p = 0; p < 5; ++p) {
            float t = ad0[p] * ((j == 1+p) ? 1.f : 0.f);
            for (int c = cstart[p]; c < cstart[p] + ccnt[p]; ++c) t += adc[c] * Ts[(6+c)*54 + j];
            Ts[(1+p)*54 + j] = t;
        }
    }
    __syncthreads();
    if (tid < 54) {                       // root row
        float t = ar[0] * ((tid == 0) ? 1.f : 0.f);
        for (int d = 0; d < 5; ++d) t += ar[1+d] * Ts[(1+d)*54 + tid];
        Ts[0*54 + tid] = t;
    }
    __syncthreads();

    for (int cc = 0; cc < 2; ++cc) {
        for (int x = tid; x < HROWS * 32; x += 256) {
            const int row = x >> 5, q = x & 31;
            const int side = q >> 4, qi = q & 15;
            const int col = g * 128 + cc * 64 + qi * 4 + side * 2048;
            f32x4 s = {0.f,0.f,0.f,0.f};
#pragma unroll
            for (int sl = 0; sl < SPLITK; ++sl)
                s += *(const f32x4*)(hpart + (size_t)sl * HSZ + (size_t)row * DIM + col);
            *(f32x4*)&gs[row * 128 + side * 64 + qi * 4] = s;
        }
        __syncthreads();

        const int p  = tid & 63;
        const int rq = tid >> 6;             // 0..3
        const int j  = g * 128 + cc * 64 + p;
        const int jj = j + 2048;
        const float e0v = edge[j], e1v = edge[2048 + j], e2v = edge[4096 + j];
        const float er0 = cosf(e0v), ei0 = sinf(e0v);
        const float er1 = cosf(e1v), ei1 = sinf(e1v);
        const float er2 = cosf(e2v), ei2 = sinf(e2v);

        float a0r = 0.f, a0i = 0.f;
#pragma unroll 6
        for (int k = 0; k < HROWS; ++k) {
            const float t0 = Ts[k];
            a0r += t0 * gs[k * 128 + p];
            a0i += t0 * gs[k * 128 + 64 + p];
        }
        const float rr = a0r, ri = a0i;

        for (int r = rq; r < HROWS; r += 4) {
            float vr, vi, scale;
            if (r == 0) {
                vr = rr; vi = ri; scale = 1.f;
            } else {
                int row1, row2 = 0;
                if (r < 6)       { row1 = r; }
                else if (r < 18) { const int c = r - 6;      row1 = 1 + PF[c]; row2 = r; }
                else             { const int c = (r - 18)/3; row1 = 1 + PF[c]; row2 = 6 + c; }

                float a1r = 0.f, a1i = 0.f;
#pragma unroll 6
                for (int k = 0; k < HROWS; ++k) {
                    const float t1 = Ts[row1 * 54 + k];
                    a1r += t1 * gs[k * 128 + p];
                    a1i += t1 * gs[k * 128 + 64 + p];
                }
                const float dr = a1r + rr * er0 - ri * ei0;
                const float di = a1i + rr * ei0 + ri * er0;
                if (r < 6) {
                    vr = dr; vi = di; scale = 0.5f;
                } else {
                    float a2r = 0.f, a2i = 0.f;
#pragma unroll 6
                    for (int k = 0; k < HROWS; ++k) {
                        const float t2 = Ts[row2 * 54 + k];
                        a2r += t2 * gs[k * 128 + p];
                        a2i += t2 * gs[k * 128 + 64 + p];
                    }
                    const float fr = a2r + dr * er1 - di * ei1;
                    const float fi = a2i + dr * ei1 + di * er1;
                    if (r < 18) {
                        vr = fr; vi = fi; scale = 1.f / 3.f;
                    } else {
                        vr = gs[r * 128 + p]      + fr * er2 - fi * ei2;
                        vi = gs[r * 128 + 64 + p] + fr * ei2 + fi * er2;
                        scale = 0.25f;
                    }
                }
            }
            vr *= scale; vi *= scale;
            if (last) {
                xo[(size_t)r * DIM + j]  = vr;
                xo[(size_t)r * DIM + jj] = vi;
            } else {
                const short h0 = f2bf(vr);
                xh[(size_t)r * DIM + j] = h0;
                xl[(size_t)r * DIM + j] = f2bf(vr - bf2f(h0));
                const short h1 = f2bf(vi);
                xh[(size_t)r * DIM + jj] = h1;
                xl[(size_t)r * DIM + jj] = f2bf(vi - bf2f(h1));
            }
        }
        __syncthreads();
    }
}

// ---------------------------------------------------------------------------
// Kernel A: gemm1 (+ p2 tail by the last block of each nb group).
// ---------------------------------------------------------------------------
__global__ __launch_bounds__(256) void gemm1_bf_g(const short* __restrict__ Ah,
                                                  const short* __restrict__ Al,
                                                  const float* __restrict__ W,
                                                  float* __restrict__ hpart,
                                                  const float* __restrict__ wA,
                                                  const float* __restrict__ wB,
                                                  const float* __restrict__ wC,
                                                  short* __restrict__ hbh,
                                                  short* __restrict__ hbl,
                                                  float* __restrict__ dotp2,
                                                  int* __restrict__ tickets)
{
    __shared__ SmemU sm;
    __shared__ int winflag;
    const int tid = threadIdx.x;
    const int bid = blockIdx.x;
    const int swz = (bid & 7) * 64 + (bid >> 3);
    const int nb  = swz & 31;
    const int ks  = swz >> 5;

    stage_bf(sm.g.lhi, sm.g.llo, Ah, Al, ks * KSLICE, tid);
    __syncthreads();
    gemm_core(sm.g.lhi, sm.g.llo, W, hpart, tid, nb, ks);

    __threadfence();
    if (tid == 0) winflag = (atomicAdd(&tickets[nb], 1) == SPLITK - 1) ? 1 : 0;
    __syncthreads();
    if (!winflag) return;
    __threadfence();
    p2_tail(nb, tid, sm.hs, hpart, wA, wB, wC, hbh, hbl, dotp2);
    if (tid == 0) tickets[nb] = 0;
}

__global__ __launch_bounds__(256) void gemm1_f32_g(const float* __restrict__ Asrc,
                                                   const float* __restrict__ W,
                                                   float* __restrict__ hpart,
                                                   const float* __restrict__ wA,
                                                   const float* __restrict__ wB,
                                                   const float* __restrict__ wC,
                                                   short* __restrict__ hbh,
                                                   short* __restrict__ hbl,
                                                   float* __restrict__ dotp2,
                                                   int* __restrict__ tickets)
{
    __shared__ SmemU sm;
    __shared__ int winflag;
    const int tid = threadIdx.x;
    const int bid = blockIdx.x;
    const int swz = (bid & 7) * 64 + (bid >> 3);
    const int nb  = swz & 31;
    const int ks  = swz >> 5;

    stage_f32(sm.g.lhi, sm.g.llo, Asrc, ks * KSLICE, tid);
    __syncthreads();
    gemm_core(sm.g.lhi, sm.g.llo, W, hpart, tid, nb, ks);

    __threadfence();
    if (tid == 0) winflag = (atomicAdd(&tickets[nb], 1) == SPLITK - 1) ? 1 : 0;
    __syncthreads();
    if (!winflag) return;
    __threadfence();
    p2_tail(nb, tid, sm.hs, hpart, wA, wB, wC, hbh, hbl, dotp2);
    if (tid == 0) tickets[nb] = 0;
}

// ---------------------------------------------------------------------------
// Kernel B: gemm2 (+ p45 tail by the last block of each pair-group g = nb&15).
// ---------------------------------------------------------------------------
__global__ __launch_bounds__(256) void gemm2_g(const short* __restrict__ Ah,
                                               const short* __restrict__ Al,
                                               const float* __restrict__ W,
                                               float* __restrict__ hpart,
                                               const float* __restrict__ dotp2,
                                               const float* __restrict__ edge,
                                               short* __restrict__ xh,
                                               short* __restrict__ xl,
                                               float* __restrict__ xo, int last,
                                               int* __restrict__ tickets)
{
    __shared__ SmemU sm;
    __shared__ int winflag;
    const int tid = threadIdx.x;
    const int bid = blockIdx.x;
    const int swz = (bid & 7) * 64 + (bid >> 3);
    const int nb  = swz & 31;
    const int ks  = swz >> 5;
    const int g   = nb & 15;

    stage_bf(sm.g.lhi, sm.g.llo, Ah, Al, ks * KSLICE, tid);
    __syncthreads();
    gemm_core(sm.g.lhi, sm.g.llo, W, hpart, tid, nb, ks);

    __threadfence();
    if (tid == 0) winflag = (atomicAdd(&tickets[g], 1) == 2 * SPLITK - 1) ? 1 : 0;
    __syncthreads();
    if (!winflag) return;
    __threadfence();
    p45_tail(g, tid, sm.t.gs, sm.t.Ts, sm.t.ds, hpart, dotp2, edge, xh, xl, xo, last);
    if (tid == 0) tickets[g] = 0;
}

// ---------------------------------------------------------------------------
extern "C" void kernel_launch(void* const* d_in, const int* in_sizes, int n_in,
                              void* d_out, int out_size, void* d_ws, size_t ws_size,
                              hipStream_t stream)
{
    const float* ce    = (const float*)d_in[0];
    const float* gatW  = (const float*)d_in[1];
    const float* attif = (const float*)d_in[2];
    const float* attfd = (const float*)d_in[3];
    const float* attdr = (const float*)d_in[4];
    const float* metaW = (const float*)d_in[5];
    const float* edge  = (const float*)d_in[6];
    float* out = (float*)d_out;

    char* w = (char*)d_ws;
    float* hpart = (float*)w;   w += (size_t)SPLITK * HSZ * 4;   // 14.2 MB
    float* dotp2 = (float*)w;   w += 32 * 324 * 4;               // 41.5 KB
    short* xbfh  = (short*)w;   w += (size_t)64 * DIM * 2;       // 512 KB each
    short* xbfl  = (short*)w;   w += (size_t)64 * DIM * 2;
    short* hbfh  = (short*)w;   w += (size_t)64 * DIM * 2;
    short* hbfl  = (short*)w;   w += (size_t)64 * DIM * 2;
    int*   tickA = (int*)w;     w += 32 * 4;
    int*   tickB = (int*)w;     w += 16 * 4;

    hipMemsetAsync(tickA, 0, 48 * sizeof(int), stream);

    for (int i = 0; i < 4; ++i) {
        const float* wif = attif + (size_t)i * 2 * DIM;
        const float* wfd = attfd + (size_t)i * 2 * DIM;
        const float* wdr = attdr + (size_t)i * 2 * DIM;
        if (i == 0)
            hipLaunchKernelGGL(gemm1_f32_g, dim3(512), dim3(256), 0, stream,
                               ce, gatW, hpart, wif, wfd, wdr, hbfh, hbfl, dotp2, tickA);
        else
            hipLaunchKernelGGL(gemm1_bf_g, dim3(512), dim3(256), 0, stream,
                               xbfh, xbfl, gatW + (size_t)i * DIM * DIM, hpart,
                               wif, wfd, wdr, hbfh, hbfl, dotp2, tickA);
        hipLaunchKernelGGL(gemm2_g, dim3(512), dim3(256), 0, stream,
                           hbfh, hbfl, metaW + (size_t)i * DIM * DIM, hpart,
                           dotp2, edge, xbfh, xbfl, out, (i == 3) ? 1 : 0, tickB);
    }
}

// Round 18
// 259.459 us; speedup vs baseline: 4.3278x; 4.2754x over previous
//
#include <hip/hip_runtime.h>
#include <hip/hip_bf16.h>

#define DIM 4096
#define HROWS 54
#define HSZ (54 * 4096)
#define SPLITK 16
#define KSLICE 256

typedef __attribute__((ext_vector_type(4))) float  f32x4;
typedef __attribute__((ext_vector_type(8))) short  s16x8;
typedef __attribute__((ext_vector_type(4))) short  s16x4;

__device__ __forceinline__ short f2bf(float f) {
    union { __hip_bfloat16 h; short s; } u;
    u.h = __float2bfloat16(f);
    return u.s;
}
__device__ __forceinline__ float bf2f(short s) {
    union { __hip_bfloat16 h; short s; } u;
    u.s = s;
    return __bfloat162float(u.h);
}
__device__ __forceinline__ float leaky(float x) { return x > 0.f ? x : 0.01f * x; }

__device__ __forceinline__ void split8(const f32x4& c0, const f32x4& c1,
                                       s16x8& h, s16x8& l) {
#pragma unroll
    for (int j = 0; j < 4; ++j) {
        short h0 = f2bf(c0[j]); h[j]     = h0; l[j]     = f2bf(c0[j] - bf2f(h0));
        short h1 = f2bf(c1[j]); h[4 + j] = h1; l[4 + j] = f2bf(c1[j] - bf2f(h1));
    }
}

// ---------------------------------------------------------------------------
// prep: bf16 split of concept_embed (padded to 64 rows), zero pads, trig tables
// ---------------------------------------------------------------------------
__global__ __launch_bounds__(256) void prep_g(const float* __restrict__ ce,
                                              const float* __restrict__ edge,
                                              short* __restrict__ xh, short* __restrict__ xl,
                                              short* __restrict__ hbh, short* __restrict__ hbl,
                                              float* __restrict__ er, float* __restrict__ ei)
{
    const int idx = blockIdx.x * 256 + threadIdx.x;
    const int row = idx >> 12;
    if (row < HROWS) {
        const float v = ce[idx];
        const short h = f2bf(v);
        xh[idx] = h; xl[idx] = f2bf(v - bf2f(h));
    } else {
        xh[idx] = 0; xl[idx] = 0; hbh[idx] = 0; hbl[idx] = 0;
    }
    if (idx < 3 * 2048) {
        const float e = edge[idx];
        er[idx] = cosf(e);
        ei[idx] = sinf(e);
    }
}

// ---------------------------------------------------------------------------
// GEMM v8: A on lgkmcnt, W on vmcnt (queue separation).
// Stage the block's 64x256 A-slice (bf16 hi+lo, 64 KB) into LDS once
// (XOR-swizzled chunks, one barrier; staging vmcnt drains BEFORE any W load
// issues). Then the W stream is the only vmcnt user, issued in consumption
// order with 2-kb lookahead -> compiler emits counted vmcnt, never drains
// prefetch. A-reuse x2 (BN=128/block). grid = 32 nb x 16 ks = 512 blocks.
// ---------------------------------------------------------------------------
__global__ __launch_bounds__(256) void gemm_g(const short* __restrict__ Ah,
                                              const short* __restrict__ Al,
                                              const float* __restrict__ W,
                                              float* __restrict__ outp)
{
    __shared__ short lhi[64 * 256];   // 32 KB
    __shared__ short llo[64 * 256];   // 32 KB

    const int tid  = threadIdx.x;
    const int lane = tid & 63;
    const int wv   = tid >> 6;
    const int nb   = blockIdx.x & 31;    // 0..31  (128-col tile)
    const int ks   = blockIdx.x >> 5;    // 0..15  (256-k slice)
    const int l15  = lane & 15;
    const int lk8  = lane >> 4;
    const int koff = ks * KSLICE;

    // ---- stage A (hi/lo) into LDS, swizzled: chunk c of row r -> slot c^(r&7)
    for (int u = tid; u < 64 * 32; u += 256) {
        const int row  = u >> 5;
        const int c    = u & 31;
        const int slot = c ^ (row & 7);
        *(s16x8*)&lhi[row * 256 + slot * 8] =
            *(const s16x8*)(Ah + (size_t)row * DIM + koff + c * 8);
        *(s16x8*)&llo[row * 256 + slot * 8] =
            *(const s16x8*)(Al + (size_t)row * DIM + koff + c * 8);
    }
    __syncthreads();   // drains staging vmcnt+lgkm; W queue starts clean

    const int ncolA = nb * 128 + wv * 16 + l15;
    const int ncolB = ncolA + 64;
    const float* wpA = W + (size_t)ncolA * DIM + koff + lk8 * 8;
    const float* wpB = W + (size_t)ncolB * DIM + koff + lk8 * 8;

    f32x4 accA0 = {0.f,0.f,0.f,0.f}, accA1 = {0.f,0.f,0.f,0.f};
    f32x4 accA2 = {0.f,0.f,0.f,0.f}, accA3 = {0.f,0.f,0.f,0.f};
    f32x4 accB0 = {0.f,0.f,0.f,0.f}, accB1 = {0.f,0.f,0.f,0.f};
    f32x4 accB2 = {0.f,0.f,0.f,0.f}, accB3 = {0.f,0.f,0.f,0.f};

// W loads for one kb (both strips, both kk halves): 8 f32x4 = 32 VGPR
#define WLD(P, KB)                                                           \
    const f32x4 P##a0 = *(const f32x4*)(wpA + (KB)*64);                      \
    const f32x4 P##a1 = *(const f32x4*)(wpA + (KB)*64 + 4);                  \
    const f32x4 P##a2 = *(const f32x4*)(wpA + (KB)*64 + 32);                 \
    const f32x4 P##a3 = *(const f32x4*)(wpA + (KB)*64 + 36);                 \
    const f32x4 P##b0 = *(const f32x4*)(wpB + (KB)*64);                      \
    const f32x4 P##b1 = *(const f32x4*)(wpB + (KB)*64 + 4);                  \
    const f32x4 P##b2 = *(const f32x4*)(wpB + (KB)*64 + 32);                 \
    const f32x4 P##b3 = *(const f32x4*)(wpB + (KB)*64 + 36);

// one (kb,kk) unit: 8 ds_read_b128 A frags + 24 MFMA (2 strips share A)
#define CKK(WA0, WA1, WB0, WB1, KB, KK)                                      \
    {   const int sl_ = (((KB)*8 + (KK)*4 + lk8) ^ (l15 & 7)) * 8;           \
        const s16x8 a0h = *(const s16x8*)&lhi[( 0 + l15)*256 + sl_];         \
        const s16x8 a1h = *(const s16x8*)&lhi[(16 + l15)*256 + sl_];         \
        const s16x8 a2h = *(const s16x8*)&lhi[(32 + l15)*256 + sl_];         \
        const s16x8 a3h = *(const s16x8*)&lhi[(48 + l15)*256 + sl_];         \
        const s16x8 a0l = *(const s16x8*)&llo[( 0 + l15)*256 + sl_];         \
        const s16x8 a1l = *(const s16x8*)&llo[(16 + l15)*256 + sl_];         \
        const s16x8 a2l = *(const s16x8*)&llo[(32 + l15)*256 + sl_];         \
        const s16x8 a3l = *(const s16x8*)&llo[(48 + l15)*256 + sl_];         \
        s16x8 bhA, blA, bhB, blB;                                            \
        split8(WA0, WA1, bhA, blA);                                          \
        split8(WB0, WB1, bhB, blB);                                          \
        accA0 = __builtin_amdgcn_mfma_f32_16x16x32_bf16(a0h, bhA, accA0, 0, 0, 0); \
        accA1 = __builtin_amdgcn_mfma_f32_16x16x32_bf16(a1h, bhA, accA1, 0, 0, 0); \
        accA2 = __builtin_amdgcn_mfma_f32_16x16x32_bf16(a2h, bhA, accA2, 0, 0, 0); \
        accA3 = __builtin_amdgcn_mfma_f32_16x16x32_bf16(a3h, bhA, accA3, 0, 0, 0); \
        accA0 = __builtin_amdgcn_mfma_f32_16x16x32_bf16(a0l, bhA, accA0, 0, 0, 0); \
        accA1 = __builtin_amdgcn_mfma_f32_16x16x32_bf16(a1l, bhA, accA1, 0, 0, 0); \
        accA2 = __builtin_amdgcn_mfma_f32_16x16x32_bf16(a2l, bhA, accA2, 0, 0, 0); \
        accA3 = __builtin_amdgcn_mfma_f32_16x16x32_bf16(a3l, bhA, accA3, 0, 0, 0); \
        accA0 = __builtin_amdgcn_mfma_f32_16x16x32_bf16(a0h, blA, accA0, 0, 0, 0); \
        accA1 = __builtin_amdgcn_mfma_f32_16x16x32_bf16(a1h, blA, accA1, 0, 0, 0); \
        accA2 = __builtin_amdgcn_mfma_f32_16x16x32_bf16(a2h, blA, accA2, 0, 0, 0); \
        accA3 = __builtin_amdgcn_mfma_f32_16x16x32_bf16(a3h, blA, accA3, 0, 0, 0); \
        accB0 = __builtin_amdgcn_mfma_f32_16x16x32_bf16(a0h, bhB, accB0, 0, 0, 0); \
        accB1 = __builtin_amdgcn_mfma_f32_16x16x32_bf16(a1h, bhB, accB1, 0, 0, 0); \
        accB2 = __builtin_amdgcn_mfma_f32_16x16x32_bf16(a2h, bhB, accB2, 0, 0, 0); \
        accB3 = __builtin_amdgcn_mfma_f32_16x16x32_bf16(a3h, bhB, accB3, 0, 0, 0); \
        accB0 = __builtin_amdgcn_mfma_f32_16x16x32_bf16(a0l, bhB, accB0, 0, 0, 0); \
        accB1 = __builtin_amdgcn_mfma_f32_16x16x32_bf16(a1l, bhB, accB1, 0, 0, 0); \
        accB2 = __builtin_amdgcn_mfma_f32_16x16x32_bf16(a2l, bhB, accB2, 0, 0, 0); \
        accB3 = __builtin_amdgcn_mfma_f32_16x16x32_bf16(a3l, bhB, accB3, 0, 0, 0); \
        accB0 = __builtin_amdgcn_mfma_f32_16x16x32_bf16(a0h, blB, accB0, 0, 0, 0); \
        accB1 = __builtin_amdgcn_mfma_f32_16x16x32_bf16(a1h, blB, accB1, 0, 0, 0); \
        accB2 = __builtin_amdgcn_mfma_f32_16x16x32_bf16(a2h, blB, accB2, 0, 0, 0); \
        accB3 = __builtin_amdgcn_mfma_f32_16x16x32_bf16(a3h, blB, accB3, 0, 0, 0); }

    // W issued in consumption order, 2-kb lookahead; A all via LDS (lgkm)
    WLD(w0_, 0) WLD(w1_, 1)
    CKK(w0_a0, w0_a1, w0_b0, w0_b1, 0, 0)
    CKK(w0_a2, w0_a3, w0_b2, w0_b3, 0, 1)
    WLD(w2_, 2)
    CKK(w1_a0, w1_a1, w1_b0, w1_b1, 1, 0)
    CKK(w1_a2, w1_a3, w1_b2, w1_b3, 1, 1)
    WLD(w3_, 3)
    CKK(w2_a0, w2_a1, w2_b0, w2_b1, 2, 0)
    CKK(w2_a2, w2_a3, w2_b2, w2_b3, 2, 1)
    CKK(w3_a0, w3_a1, w3_b0, w3_b1, 3, 0)
    CKK(w3_a2, w3_a3, w3_b2, w3_b3, 3, 1)

#undef WLD
#undef CKK

    float* op = outp + (size_t)ks * HSZ;
#pragma unroll
    for (int mt = 0; mt < 4; ++mt) {
        const f32x4 a = (mt == 0) ? accA0 : (mt == 1) ? accA1 : (mt == 2) ? accA2 : accA3;
        const f32x4 b = (mt == 0) ? accB0 : (mt == 1) ? accB1 : (mt == 2) ? accB2 : accB3;
#pragma unroll
        for (int r = 0; r < 4; ++r) {
            const int m = mt * 16 + lk8 * 4 + r;
            if (m < HROWS) {
                op[(size_t)m * DIM + ncolA] = a[r];
                op[(size_t)m * DIM + ncolB] = b[r];
            }
        }
    }
}

// ---------------------------------------------------------------------------
// p2: reduce split-K partials -> bf16 hi/lo of h + fused attention-dot partials
// ---------------------------------------------------------------------------
__global__ __launch_bounds__(256) void p2_g(const float* __restrict__ hpart,
                                            const float* __restrict__ wA,
                                            const float* __restrict__ wB,
                                            const float* __restrict__ wC,
                                            short* __restrict__ hbh, short* __restrict__ hbl,
                                            float* __restrict__ dotp)
{
    const int vb  = blockIdx.x;          // 0..215
    const int tid = threadIdx.x;
    const int i   = vb * 1024 + tid * 4;
    const int col = i & (DIM - 1);
    f32x4 s = {0.f,0.f,0.f,0.f};
#pragma unroll
    for (int sl = 0; sl < SPLITK; ++sl) s += *(const f32x4*)(hpart + (size_t)sl * HSZ + i);

    s16x4 vh, vl;
#pragma unroll
    for (int j = 0; j < 4; ++j) {
        const short h = f2bf(s[j]);
        vh[j] = h; vl[j] = f2bf(s[j] - bf2f(h));
    }
    *(s16x4*)(hbh + i) = vh;
    *(s16x4*)(hbl + i) = vl;

    float a0=0,a1=0,a2=0,a3=0,a4=0,a5=0;
#pragma unroll
    for (int j = 0; j < 4; ++j) {
        const float sv = s[j];
        const int c = col + j;
        a0 += sv * wA[c]; a1 += sv * wA[DIM + c];
        a2 += sv * wB[c]; a3 += sv * wB[DIM + c];
        a4 += sv * wC[c]; a5 += sv * wC[DIM + c];
    }
#pragma unroll
    for (int off = 32; off > 0; off >>= 1) {
        a0 += __shfl_down(a0, off); a1 += __shfl_down(a1, off);
        a2 += __shfl_down(a2, off); a3 += __shfl_down(a3, off);
        a4 += __shfl_down(a4, off); a5 += __shfl_down(a5, off);
    }
    if ((tid & 63) == 0) {
        float* d = dotp + ((size_t)vb * 4 + (tid >> 6)) * 6;
        d[0]=a0; d[1]=a1; d[2]=a2; d[3]=a3; d[4]=a4; d[5]=a5;
    }
}

// ---------------------------------------------------------------------------
// p45: per-block {inline split-K reduce of its 8 column-pairs -> LDS,
// T rebuild, fused applyT + rope}. grid 256 x 256 (full-CU spread).
// ---------------------------------------------------------------------------
__global__ __launch_bounds__(256) void p45_g(const float* __restrict__ hpart,
                                             const float* __restrict__ dotp,
                                             const float* __restrict__ er,
                                             const float* __restrict__ ei,
                                             short* __restrict__ xh, short* __restrict__ xl,
                                             float* __restrict__ xo, int last)
{
    const int b   = blockIdx.x;          // 0..255
    const int tid = threadIdx.x;
    __shared__ float gs[HROWS][16];      // c<8 -> j=b*8+c, c>=8 -> jj
    __shared__ float ds[324];
    __shared__ float Ts[54][54];
    __shared__ float ad0[5], adc[12], ar[6], fdot3[12], fdot5[12], ddot5[5];

    // ---- phase 1: inline split-K reduce of this block's 54x16 gsum tile ----
    for (int x = tid; x < HROWS * 16; x += 256) {
        const int row = x >> 4;
        const int c   = x & 15;
        const int gj  = (c < 8) ? (b * 8 + c) : (2048 + b * 8 + (c - 8));
        float s = 0.f;
#pragma unroll
        for (int sl = 0; sl < SPLITK; ++sl)
            s += hpart[(size_t)sl * HSZ + (size_t)row * DIM + gj];
        gs[row][c] = s;
    }

    // ---- T build ----
    for (int x = tid; x < 324; x += 256) {
        const int r_ = x / 6, v = x % 6;
        float s = 0.f;
#pragma unroll
        for (int u = 0; u < 16; ++u) s += dotp[(size_t)(r_ * 16 + u) * 6 + v];
        ds[x] = s;
    }
    for (int i = tid; i < 54 * 54; i += 256) ((float*)Ts)[i] = 0.f;
    __syncthreads();

    if (tid < 12) {                       // level if
        const int p = tid;
        const float u = ds[(6+p)*6 + 0];
        const float ss = leaky(u + ds[(6+p)*6 + 1]);
        float sc[3], mx = ss;
#pragma unroll
        for (int j = 0; j < 3; ++j) { sc[j] = leaky(u + ds[(18+3*p+j)*6 + 1]); mx = fmaxf(mx, sc[j]); }
        float e0 = expf(ss - mx), s = e0, ec[3];
#pragma unroll
        for (int j = 0; j < 3; ++j) { ec[j] = expf(sc[j] - mx); s += ec[j]; }
        const float inv = 1.f / s;
        const float a0 = e0 * inv;
        float f3 = a0 * ds[(6+p)*6 + 3];
        float f5 = a0 * ds[(6+p)*6 + 5];
        Ts[6+p][6+p] = a0;
#pragma unroll
        for (int j = 0; j < 3; ++j) {
            const float a = ec[j] * inv;
            Ts[6+p][18+3*p+j] = a;
            f3 += a * ds[(18+3*p+j)*6 + 3];
            f5 += a * ds[(18+3*p+j)*6 + 5];
        }
        fdot3[p] = f3; fdot5[p] = f5;
    }
    __syncthreads();

    if (tid < 5) {                        // level fd
        const int p = tid;
        const int cstart[5] = {0,3,5,8,10};
        const int ccnt[5]   = {3,2,3,2,2};
        const float u = ds[(1+p)*6 + 2];
        const float ss = leaky(u + ds[(1+p)*6 + 3]);
        const int n = ccnt[p], c0 = cstart[p];
        float mx = ss, sc[3];
        for (int j = 0; j < n; ++j) { sc[j] = leaky(u + fdot3[c0+j]); mx = fmaxf(mx, sc[j]); }
        float e0 = expf(ss - mx), s = e0, ec[3];
        for (int j = 0; j < n; ++j) { ec[j] = expf(sc[j] - mx); s += ec[j]; }
        const float inv = 1.f / s;
        ad0[p] = e0 * inv;
        float d5 = ad0[p] * ds[(1+p)*6 + 5];
        for (int j = 0; j < n; ++j) {
            const float a = ec[j] * inv;
            adc[c0+j] = a;
            d5 += a * fdot5[c0+j];
        }
        ddot5[p] = d5;
    }
    __syncthreads();

    if (tid == 0) {                       // level dr
        const float u = ds[0*6 + 4];
        const float ss = leaky(u + ds[0*6 + 5]);
        float mx = ss, sc[5];
#pragma unroll
        for (int d = 0; d < 5; ++d) { sc[d] = leaky(u + ddot5[d]); mx = fmaxf(mx, sc[d]); }
        float e0 = expf(ss - mx), s = e0, ec[5];
#pragma unroll
        for (int d = 0; d < 5; ++d) { ec[d] = expf(sc[d] - mx); s += ec[d]; }
        const float inv = 1.f / s;
        ar[0] = e0 * inv;
#pragma unroll
        for (int d = 0; d < 5; ++d) ar[1+d] = ec[d] * inv;
    }
    for (int q = tid; q < 36; q += 256) Ts[18+q][18+q] = 1.f;
    __syncthreads();

    if (tid < 54) {                       // domain rows
        const int j = tid;
        const int cstart[5] = {0,3,5,8,10};
        const int ccnt[5]   = {3,2,3,2,2};
        for (int p = 0; p < 5; ++p) {
            float t = ad0[p] * ((j == 1+p) ? 1.f : 0.f);
            for (int c = cstart[p]; c < cstart[p] + ccnt[p]; ++c) t += adc[c] * Ts[6+c][j];
            Ts[1+p][j] = t;
        }
    }
    __syncthreads();
    if (tid < 54) {                       // root row
        float t = ar[0] * ((tid == 0) ? 1.f : 0.f);
        for (int d = 0; d < 5; ++d) t += ar[1+d] * Ts[1+d][tid];
        Ts[0][tid] = t;
    }
    __syncthreads();

    // ---- phase 2: fused applyT + rope; thread = (pair p, r-group rq) ----
    const int p  = tid & 7;              // pair index within block
    const int rq = tid >> 3;             // 0..31
    const int j  = b * 8 + p;            // 0..2047
    const int jj = j + 2048;
    constexpr int PF[12] = {0,0,0,1,1,2,2,2,3,3,4,4};

    const float er0 = er[j],        ei0 = ei[j];
    const float er1 = er[2048 + j], ei1 = ei[2048 + j];
    const float er2 = er[4096 + j], ei2 = ei[4096 + j];

    float a0r = 0.f, a0i = 0.f;
#pragma unroll 6
    for (int k = 0; k < HROWS; ++k) {
        const float t0 = Ts[0][k];
        a0r += t0 * gs[k][p];
        a0i += t0 * gs[k][p + 8];
    }
    const float rr = a0r, ri = a0i;

    for (int r = rq; r < HROWS; r += 32) {
        float vr, vi, scale;
        if (r == 0) {
            vr = rr; vi = ri; scale = 1.f;
        } else {
            int row1, row2 = 0;
            if (r < 6)       { row1 = r; }
            else if (r < 18) { const int c = r - 6;      row1 = 1 + PF[c]; row2 = r; }
            else             { const int c = (r - 18)/3; row1 = 1 + PF[c]; row2 = 6 + c; }

            float a1r = 0.f, a1i = 0.f;
#pragma unroll 6
            for (int k = 0; k < HROWS; ++k) {
                const float t1 = Ts[row1][k];
                a1r += t1 * gs[k][p];
                a1i += t1 * gs[k][p + 8];
            }
            const float dr = a1r + rr * er0 - ri * ei0;
            const float di = a1i + rr * ei0 + ri * er0;
            if (r < 6) {
                vr = dr; vi = di; scale = 0.5f;
            } else {
                float a2r = 0.f, a2i = 0.f;
#pragma unroll 6
                for (int k = 0; k < HROWS; ++k) {
                    const float t2 = Ts[row2][k];
                    a2r += t2 * gs[k][p];
                    a2i += t2 * gs[k][p + 8];
                }
                const float fr = a2r + dr * er1 - di * ei1;
                const float fi = a2i + dr * ei1 + di * er1;
                if (r < 18) {
                    vr = fr; vi = fi; scale = 1.f / 3.f;
                } else {
                    vr = gs[r][p]     + fr * er2 - fi * ei2;
                    vi = gs[r][p + 8] + fr * ei2 + fi * er2;
                    scale = 0.25f;
                }
            }
        }
        vr *= scale; vi *= scale;
        if (last) {
            xo[(size_t)r * DIM + j]  = vr;
            xo[(size_t)r * DIM + jj] = vi;
        } else {
            const short h0 = f2bf(vr);
            xh[(size_t)r * DIM + j] = h0;
            xl[(size_t)r * DIM + j] = f2bf(vr - bf2f(h0));
            const short h1 = f2bf(vi);
            xh[(size_t)r * DIM + jj] = h1;
            xl[(size_t)r * DIM + jj] = f2bf(vi - bf2f(h1));
        }
    }
}

// ---------------------------------------------------------------------------
extern "C" void kernel_launch(void* const* d_in, const int* in_sizes, int n_in,
                              void* d_out, int out_size, void* d_ws, size_t ws_size,
                              hipStream_t stream)
{
    const float* ce    = (const float*)d_in[0];
    const float* gatW  = (const float*)d_in[1];
    const float* attif = (const float*)d_in[2];
    const float* attfd = (const float*)d_in[3];
    const float* attdr = (const float*)d_in[4];
    const float* metaW = (const float*)d_in[5];
    const float* edge  = (const float*)d_in[6];
    float* out = (float*)d_out;

    char* w = (char*)d_ws;
    float* hpart = (float*)w;   w += (size_t)SPLITK * HSZ * 4;   // 14.2 MB
    float* dotp  = (float*)w;   w += 6144 * 4;                   // 864*6 used
    float* er    = (float*)w;   w += 3 * 2048 * 4;
    float* ei    = (float*)w;   w += 3 * 2048 * 4;
    short* xbfh  = (short*)w;   w += (size_t)64 * DIM * 2;       // 512 KB each
    short* xbfl  = (short*)w;   w += (size_t)64 * DIM * 2;
    short* hbfh  = (short*)w;   w += (size_t)64 * DIM * 2;
    short* hbfl  = (short*)w;   w += (size_t)64 * DIM * 2;

    hipLaunchKernelGGL(prep_g, dim3(1024), dim3(256), 0, stream,
                       ce, edge, xbfh, xbfl, hbfh, hbfl, er, ei);

    for (int i = 0; i < 4; ++i) {
        hipLaunchKernelGGL(gemm_g, dim3(512), dim3(256), 0, stream,
                           xbfh, xbfl, gatW + (size_t)i * DIM * DIM, hpart);
        hipLaunchKernelGGL(p2_g, dim3(216), dim3(256), 0, stream,
                           hpart, attif + (size_t)i * 2 * DIM, attfd + (size_t)i * 2 * DIM,
                           attdr + (size_t)i * 2 * DIM, hbfh, hbfl, dotp);
        hipLaunchKernelGGL(gemm_g, dim3(512), dim3(256), 0, stream,
                           hbfh, hbfl, metaW + (size_t)i * DIM * DIM, hpart);
        hipLaunchKernelGGL(p45_g, dim3(256), dim3(256), 0, stream,
                           hpart, dotp, er, ei, xbfh, xbfl, out, (i == 3) ? 1 : 0);
    }
}